// Round 3
// baseline (131.240 us; speedup 1.0000x reference)
//
#include <hip/hip_runtime.h>

// FRAP forward — fully fused single-workgroup kernel (round 3).
// R2 result: 53us, VALUBusy ~25% on-CU -> ~75% stall. Diagnosis: K-deep
// phases run 1-2 waves/SIMD with exposed dep chains + L2-latency weight
// loads. R3: (a) K-split all deep phases across lanes + shuffle reduce
// (P2/P6: 1024 thr, conv h2: 896 thr 16ch x 8-way K, P3/P7/P10/P13 wide);
// (b) two-sink warm: conv weights stay in flight across P0-P7;
// (c) P4 gather folded into P5; per-thread weight hoists in P8/P11.
//
// LDS map (floats):
//   early (all consumed before P8): feat @0(112) dh1 @128(2048)
//     dh2 @2176(256) dem @2432(32) ch1 @2560(1024) ch2 @3584(256)
//   conv: big @0 (14336, swizzled [s][c])  mid @14336 (32x56 [o][s])
//         dp @16128(32)  Hd @16160(112)  h3 @0(448, after P12)
// Swizzle: (s,c) at big[s*256 + ((c>>2)^(s&7))*4 + (c&3)] -> balanced banks.

#define DEV __device__ __forceinline__

DEV float dot4(float4 a, float4 b) {
    return a.x * b.x + a.y * b.y + a.z * b.z + a.w * b.w;
}

DEV float warm_arr(const float* __restrict__ p, int n4, int t, float sink) {
    const float4* p4 = (const float4*)p;
    for (int i = t; i < n4; i += 1024) {
        float4 v = p4[i];
        sink += v.x + v.y + v.z + v.w;
    }
    return sink;
}

// conv h2: big (swizzled [s][256]) -> relu(w2(32x256)@.) -> mid[o*56+s]
// 896 threads: u=t>>3 (s=u%56, og=u/56 -> 16 ch), kq=t&7 (K-slice of 32).
DEV void conv_h2_phase(const float* __restrict__ big, const float* __restrict__ w2,
                       const float* __restrict__ b2, float* __restrict__ mid, int t)
{
    if (t < 896) {
        int kq = t & 7;
        int u  = t >> 3;            // 0..111
        int s  = u % 56, og = u / 56;   // og 0..1 -> 16 channels
        const float4* hrow = (const float4*)(big + (s << 8));
        int sw = s & 7;
        float acc[16];
#pragma unroll
        for (int q = 0; q < 16; ++q) acc[q] = 0.0f;
#pragma unroll
        for (int e = 0; e < 8; ++e) {
            int g = kq * 8 + e;
            float4 v = hrow[g ^ sw];
#pragma unroll
            for (int q = 0; q < 16; ++q) {
                float4 w = ((const float4*)(w2 + (og * 16 + q) * 256))[g];
                acc[q] += dot4(v, w);
            }
        }
#pragma unroll
        for (int q = 0; q < 16; ++q) {
            float a = acc[q];
            a += __shfl_xor(a, 1);
            a += __shfl_xor(a, 2);
            a += __shfl_xor(a, 4);
            acc[q] = a;
        }
        if (kq == 0) {
#pragma unroll
            for (int q = 0; q < 16; ++q)
                mid[(og * 16 + q) * 56 + s] = fmaxf(acc[q] + b2[og * 16 + q], 0.0f);
        }
    }
}

__global__ __launch_bounds__(1024, 1) void frap_kernel(
    const float* __restrict__ waiting, const float* __restrict__ phase,
    const float* __restrict__ wtime_mu, const float* __restrict__ wtime_sigma,
    const float* __restrict__ wtime_max,
    const float* __restrict__ i_pos, const float* __restrict__ j_pos,
    const float* __restrict__ d_w1, const float* __restrict__ d_b1,
    const float* __restrict__ d_w2, const float* __restrict__ d_b2,
    const float* __restrict__ d_w3, const float* __restrict__ d_b3,
    const float* __restrict__ c_w1, const float* __restrict__ c_b1,
    const float* __restrict__ c_w2, const float* __restrict__ c_b2,
    const float* __restrict__ c_w3, const float* __restrict__ c_b3,
    const float* __restrict__ dD_w1, const float* __restrict__ dD_b1,
    const float* __restrict__ dD_w2, const float* __restrict__ dD_b2,
    const float* __restrict__ dD_w3, const float* __restrict__ dD_b3,
    const float* __restrict__ cC_w1, const float* __restrict__ cC_b1,
    const float* __restrict__ cC_w2, const float* __restrict__ cC_b2,
    const float* __restrict__ cC_w3, const float* __restrict__ cC_b3,
    const float* __restrict__ cC_w4, const float* __restrict__ cC_b4,
    float* __restrict__ out)
{
    __shared__ __align__(16) float sm[16384];   // 64 KB
    const int t = threadIdx.x;

    float* feat = sm;          // 112
    float* dh1  = sm + 128;    // 2048
    float* dh2  = sm + 2176;   // 256
    float* dem  = sm + 2432;   // 32
    float* ch1  = sm + 2560;   // 1024
    float* ch2  = sm + 3584;   // 256
    float* big  = sm;          // 14336 (swizzled [s][256])
    float* mid  = sm + 14336;  // 1792  [o][56]
    float* dp   = sm + 16128;  // 32
    float* Hd   = sm + 16160;  // 112
    float* h3   = sm;          // 448 (reuses big after P12)

    // ---- Warm, sink 1: early-net weights (needed P1..P7). Issued now,
    // consumed immediately so P1 hits warm cache.
    float snk1 = 0.0f;
    snk1 = warm_arr(d_w1,  896, t, snk1);
    snk1 = warm_arr(d_b1,   64, t, snk1);
    snk1 = warm_arr(d_w2, 2048, t, snk1);
    snk1 = warm_arr(d_b2,    8, t, snk1);
    snk1 = warm_arr(d_w3,   32, t, snk1);
    snk1 = warm_arr(d_b3,    1, t, snk1);
    snk1 = warm_arr(c_w1,  256, t, snk1);
    snk1 = warm_arr(c_b1,   32, t, snk1);
    snk1 = warm_arr(c_w2, 1024, t, snk1);
    snk1 = warm_arr(c_b2,    8, t, snk1);
    snk1 = warm_arr(c_w3,   32, t, snk1);
    snk1 = warm_arr(c_b3,    1, t, snk1);
    // ---- Warm, sink 2: conv weights (needed from P8). Loads issue here,
    // sink consumed only after P7 -> latency hides under P0..P7.
    float snk2 = 0.0f;
    snk2 = warm_arr(dD_w1,  512, t, snk2);
    snk2 = warm_arr(dD_b1,   64, t, snk2);
    snk2 = warm_arr(dD_w2, 2048, t, snk2);
    snk2 = warm_arr(dD_b2,    8, t, snk2);
    snk2 = warm_arr(dD_w3,   16, t, snk2);
    snk2 = warm_arr(cC_w1,  192, t, snk2);
    snk2 = warm_arr(cC_b1,   64, t, snk2);
    snk2 = warm_arr(cC_w2, 2048, t, snk2);
    snk2 = warm_arr(cC_b2,    8, t, snk2);
    snk2 = warm_arr(cC_w3,   64, t, snk2);
    snk2 = warm_arr(cC_b3,    2, t, snk2);
    snk2 = warm_arr(cC_w4,   14, t, snk2);
    asm volatile("" :: "v"(snk1));   // early weights resident before P1

    // ---- P0: feat (8 x 14)
    if (t < 112) {
        int l = t / 14, c = t - l * 14;
        float v;
        if      (c == 0) v = i_pos[0];
        else if (c == 1) v = j_pos[0];
        else if (c == 2) v = wtime_mu[l];
        else if (c == 3) v = wtime_sigma[l];
        else if (c == 4) v = wtime_max[l];
        else if (c == 5) v = waiting[l];
        else             v = phase[c - 6];
        feat[t] = v;
    }
    __syncthreads();

    // ---- P1: demand h1 (8x256), K=14. 1024 thr x 2 outs.
    for (int idx = t; idx < 2048; idx += 1024) {
        int l = idx >> 8, o = idx & 255;
        const float* w = d_w1 + o * 14;
        const float* f = feat + l * 14;
        float acc = d_b1[o];
#pragma unroll
        for (int c = 0; c < 14; ++c) acc = fmaf(f[c], w[c], acc);
        dh1[idx] = fmaxf(acc, 0.0f);
    }
    __syncthreads();

    // ---- P2: demand h2 (8x32), K=256. 1024 thr: 4-way K-split.
    {
        int l = t >> 7, o = (t >> 2) & 31, kq = t & 3;
        const float4* w = (const float4*)(d_w2 + o * 256) + kq * 16;
        const float4* h = (const float4*)(dh1 + l * 256) + kq * 16;
        float acc = 0.0f;
#pragma unroll
        for (int g = 0; g < 16; ++g) acc += dot4(h[g], w[g]);
        acc += __shfl_xor(acc, 1);
        acc += __shfl_xor(acc, 2);
        if (kq == 0) dh2[l * 32 + o] = fmaxf(acc + d_b2[o], 0.0f);
    }
    __syncthreads();

    // ---- P3: demand out (8x4), K=32. 128 thr: 4-way K-split.
    if (t < 128) {
        int u = t >> 2, kq = t & 3;
        int l = u >> 2, o = u & 3;
        const float4* w = (const float4*)(d_w3 + o * 32) + kq * 2;
        const float4* h = (const float4*)(dh2 + l * 32) + kq * 2;
        float acc = dot4(h[0], w[0]) + dot4(h[1], w[1]);
        acc += __shfl_xor(acc, 1);
        acc += __shfl_xor(acc, 2);
        if (kq == 0) dem[u] = acc + d_b3[o];
    }
    __syncthreads();

    // ---- P5: coupled h1 (8x128), K=8; PAIRS gather folded in.
    {
        int p = t >> 7, o = t & 127;
        int a0 = p & 3;
        int a1 = (p < 4) ? (4 + (p & 3)) : (4 + ((p & 3) ^ 1));
        float4 va = ((const float4*)dem)[a0];
        float4 vb = ((const float4*)dem)[a1];
        const float4* w = (const float4*)(c_w1 + o * 8);
        float acc = c_b1[o] + dot4(va, w[0]) + dot4(vb, w[1]);
        ch1[t] = fmaxf(acc, 0.0f);
    }
    __syncthreads();

    // ---- P6: coupled h2 (8x32), K=128. 1024 thr: 4-way K-split.
    {
        int l = t >> 7, o = (t >> 2) & 31, kq = t & 3;
        const float4* w = (const float4*)(c_w2 + o * 128) + kq * 8;
        const float4* h = (const float4*)(ch1 + l * 128) + kq * 8;
        float acc = 0.0f;
#pragma unroll
        for (int g = 0; g < 8; ++g) acc += dot4(h[g], w[g]);
        acc += __shfl_xor(acc, 1);
        acc += __shfl_xor(acc, 2);
        if (kq == 0) ch2[l * 32 + o] = fmaxf(acc + c_b2[o], 0.0f);
    }
    __syncthreads();

    // ---- P7: dp (8x4), K=32. 128 thr: 4-way K-split.
    if (t < 128) {
        int u = t >> 2, kq = t & 3;
        int l = u >> 2, o = u & 3;
        const float4* w = (const float4*)(c_w3 + o * 32) + kq * 2;
        const float4* h = (const float4*)(ch2 + l * 32) + kq * 2;
        float acc = dot4(h[0], w[0]) + dot4(h[1], w[1]);
        acc += __shfl_xor(acc, 1);
        acc += __shfl_xor(acc, 2);
        if (kq == 0) dp[u] = acc + c_b3[o];
    }
    asm volatile("" :: "v"(snk2));   // conv weights resident before P8
    __syncthreads();

    // ---- P8: conv_D h1 (256 x 56), K=8 from dp. Weight row hoisted.
    {
        const float4* dp4 = (const float4*)dp;
        int o = t & 255;
        const float4* wrow = (const float4*)(dD_w1 + o * 8);
        float4 w0 = wrow[0], w1 = wrow[1];
        float bias = dD_b1[o];
#pragma unroll
        for (int it = 0; it < 14; ++it) {
            int s = (t >> 8) + it * 4;
            int i = s / 7, k = s - i * 7;
            int j = k + (k >= i ? 1 : 0);
            float acc = bias + dot4(dp4[i], w0) + dot4(dp4[j], w1);
            big[(s << 8) + (o ^ ((s & 7) << 2))] = fmaxf(acc, 0.0f);
        }
    }
    __syncthreads();

    // ---- P9: conv_D h2 (32 x 56), K=256
    conv_h2_phase(big, dD_w2, dD_b2, mid, t);
    __syncthreads();

    // ---- P10: conv_D h3 -> Hd (2 x 56), K=32. 448 thr: 4-way K-split.
    if (t < 448) {
        int u = t >> 2, kq = t & 3;
        int o = u / 56, s = u % 56;
        float acc = 0.0f;
#pragma unroll
        for (int cc = 0; cc < 8; ++cc) {
            int c = kq * 8 + cc;
            acc = fmaf(mid[c * 56 + s], dD_w3[o * 32 + c], acc);
        }
        acc += __shfl_xor(acc, 1);
        acc += __shfl_xor(acc, 2);
        if (kq == 0) Hd[o * 56 + s] = acc + dD_b3[o];
    }
    __syncthreads();

    // ---- P11: conv_C h1 (256 x 56): H_c channel 2 is zero -> 2 taps.
    {
        int o = t & 255;
        float w0 = cC_w1[o * 3], w1 = cC_w1[o * 3 + 1];
        float bias = cC_b1[o];
#pragma unroll
        for (int it = 0; it < 14; ++it) {
            int s = (t >> 8) + it * 4;
            float acc = bias + Hd[s] * w0 + Hd[56 + s] * w1;
            big[(s << 8) + (o ^ ((s & 7) << 2))] = fmaxf(acc, 0.0f);
        }
    }
    __syncthreads();

    // ---- P12: conv_C h2 (32 x 56), K=256
    conv_h2_phase(big, cC_w2, cC_b2, mid, t);
    __syncthreads();

    // ---- P13: conv_C h3 (8 x 56), K=32, relu. 896 thr: 2-way K-split.
    if (t < 896) {
        int u = t >> 1, kq = t & 1;
        int o = u / 56, s = u % 56;
        float acc = 0.0f;
#pragma unroll
        for (int cc = 0; cc < 16; ++cc) {
            int c = kq * 16 + cc;
            acc = fmaf(mid[c * 56 + s], cC_w3[o * 32 + c], acc);
        }
        acc += __shfl_xor(acc, 1);
        if (kq == 0) h3[o * 56 + s] = fmaxf(acc + cC_b3[o], 0.0f);
    }
    __syncthreads();

    // ---- P14: final (1,7) conv: out[h] = sum_{c,w} cC_w4[c][w]*h3[c][h*7+w]+b4
    if (t < 64) {
        int h = t >> 3, c = t & 7;
        float p = 0.0f;
#pragma unroll
        for (int w = 0; w < 7; ++w)
            p = fmaf(cC_w4[c * 7 + w], h3[c * 56 + h * 7 + w], p);
#pragma unroll
        for (int off = 1; off < 8; off <<= 1) p += __shfl_xor(p, off);
        if (c == 0) out[h] = p + cC_b4[0];
    }
}

extern "C" void kernel_launch(void* const* d_in, const int* in_sizes, int n_in,
                              void* d_out, int out_size, void* d_ws, size_t ws_size,
                              hipStream_t stream) {
    (void)in_sizes; (void)n_in; (void)d_ws; (void)ws_size; (void)out_size;
    const float* a[33];
    for (int i = 0; i < 33; ++i) a[i] = (const float*)d_in[i];
    frap_kernel<<<dim3(1), dim3(1024), 0, stream>>>(
        a[0], a[1], a[2], a[3], a[4], a[5], a[6],
        a[7], a[8], a[9], a[10], a[11], a[12],
        a[13], a[14], a[15], a[16], a[17], a[18],
        a[19], a[20], a[21], a[22], a[23], a[24],
        a[25], a[26], a[27], a[28], a[29], a[30], a[31], a[32],
        (float*)d_out);
}

// Round 4
// 44.080 us; speedup vs baseline: 2.9773x; 2.9773x over previous
//
#include <hip/hip_runtime.h>

// FRAP forward — fully fused single-workgroup kernel (round 4).
// R3 regressed (137us): conv acc[16] spilled to scratch (WRITE_SIZE 206KB).
// R4 = R2 skeleton (53us, no spills) + scalar-cache weight delivery:
//   conv h2 (P9/P12) and P13 map channel-group -> wave via
//   readfirstlane(t>>6), so weight addrs are SGPR -> s_load streams,
//   v_fma with SGPR operand; no per-lane weight loads. acc[4] max.
// Small phases keep R3's K-split (scalar accs, spill-proof).
// NOTE: __syncthreads drains vmcnt(0) -> no load survives a barrier; warm
// is a single front burst consumed before P0.
//
// LDS map (floats):
//   early (consumed before P8): feat @0(112) dh1 @128(2048) dh2 @2176(256)
//     dem @2432(32) ch1 @2560(1024) ch2 @3584(256)
//   conv: big @0 (14336, swizzled [s][c])  mid @14336 (32x56 [o][s])
//         dp @16128(32)  Hd @16160(112)  h3 @0(448, after P12)
// Swizzle: (s,c) at big[s*256 + ((c>>2)^(s&7))*4 + (c&3)].

#define DEV __device__ __forceinline__

DEV float dot4a(float acc, float4 a, float4 b) {
    acc = fmaf(a.x, b.x, acc);
    acc = fmaf(a.y, b.y, acc);
    acc = fmaf(a.z, b.z, acc);
    acc = fmaf(a.w, b.w, acc);
    return acc;
}

DEV float warm_arr(const float* __restrict__ p, int n4, int t, float sink) {
    const float4* p4 = (const float4*)p;
    for (int i = t; i < n4; i += 1024) {
        float4 v = p4[i];
        sink += v.x + v.y + v.z + v.w;
    }
    return sink;
}

// conv h2: big (swizzled [s][256]) -> relu(W(32x256)@.) -> mid[o*56+s].
// 8 waves; wave wv owns channels 4wv..4wv+3 (uniform -> s_load weights);
// lanes = spatial s (56 of 64 active). acc[4], ~25 VGPR.
DEV void conv_h2_scalar(const float* __restrict__ big, const float* __restrict__ w2g,
                        const float* __restrict__ b2g, float* __restrict__ mid, int t)
{
    int wv = __builtin_amdgcn_readfirstlane(t >> 6);   // wave id, uniform
    int s  = t & 63;
    if (wv < 8 && s < 56) {
        const float4* hrow = (const float4*)(big + (s << 8));
        int sw = s & 7;
        const float4* w0 = (const float4*)(w2g + (wv * 4 + 0) * 256);
        const float4* w1 = (const float4*)(w2g + (wv * 4 + 1) * 256);
        const float4* w2 = (const float4*)(w2g + (wv * 4 + 2) * 256);
        const float4* w3 = (const float4*)(w2g + (wv * 4 + 3) * 256);
        float a0 = 0.0f, a1 = 0.0f, a2 = 0.0f, a3 = 0.0f;
#pragma unroll 8
        for (int g = 0; g < 64; ++g) {
            float4 v = hrow[g ^ sw];
            a0 = dot4a(a0, v, w0[g]);
            a1 = dot4a(a1, v, w1[g]);
            a2 = dot4a(a2, v, w2[g]);
            a3 = dot4a(a3, v, w3[g]);
        }
        mid[(wv * 4 + 0) * 56 + s] = fmaxf(a0 + b2g[wv * 4 + 0], 0.0f);
        mid[(wv * 4 + 1) * 56 + s] = fmaxf(a1 + b2g[wv * 4 + 1], 0.0f);
        mid[(wv * 4 + 2) * 56 + s] = fmaxf(a2 + b2g[wv * 4 + 2], 0.0f);
        mid[(wv * 4 + 3) * 56 + s] = fmaxf(a3 + b2g[wv * 4 + 3], 0.0f);
    }
}

__global__ __launch_bounds__(1024, 1) void frap_kernel(
    const float* __restrict__ waiting, const float* __restrict__ phase,
    const float* __restrict__ wtime_mu, const float* __restrict__ wtime_sigma,
    const float* __restrict__ wtime_max,
    const float* __restrict__ i_pos, const float* __restrict__ j_pos,
    const float* __restrict__ d_w1, const float* __restrict__ d_b1,
    const float* __restrict__ d_w2, const float* __restrict__ d_b2,
    const float* __restrict__ d_w3, const float* __restrict__ d_b3,
    const float* __restrict__ c_w1, const float* __restrict__ c_b1,
    const float* __restrict__ c_w2, const float* __restrict__ c_b2,
    const float* __restrict__ c_w3, const float* __restrict__ c_b3,
    const float* __restrict__ dD_w1, const float* __restrict__ dD_b1,
    const float* __restrict__ dD_w2, const float* __restrict__ dD_b2,
    const float* __restrict__ dD_w3, const float* __restrict__ dD_b3,
    const float* __restrict__ cC_w1, const float* __restrict__ cC_b1,
    const float* __restrict__ cC_w2, const float* __restrict__ cC_b2,
    const float* __restrict__ cC_w3, const float* __restrict__ cC_b3,
    const float* __restrict__ cC_w4, const float* __restrict__ cC_b4,
    float* __restrict__ out)
{
    __shared__ __align__(16) float sm[16384];   // 64 KB
    const int t = threadIdx.x;

    float* feat = sm;          // 112
    float* dh1  = sm + 128;    // 2048
    float* dh2  = sm + 2176;   // 256
    float* dem  = sm + 2432;   // 32
    float* ch1  = sm + 2560;   // 1024
    float* ch2  = sm + 3584;   // 256
    float* big  = sm;          // 14336 (swizzled [s][256])
    float* mid  = sm + 14336;  // 1792  [o][s]
    float* dp   = sm + 16128;  // 32
    float* Hd   = sm + 16160;  // 112
    float* h3   = sm;          // 448 (reuses big after P12)

    // ---- Warm: one parallel coalesced burst over the whole weight set.
    {
        float snk = 0.0f;
        snk = warm_arr(d_w1,  896, t, snk);
        snk = warm_arr(d_b1,   64, t, snk);
        snk = warm_arr(d_w2, 2048, t, snk);
        snk = warm_arr(d_b2,    8, t, snk);
        snk = warm_arr(d_w3,   32, t, snk);
        snk = warm_arr(d_b3,    1, t, snk);
        snk = warm_arr(c_w1,  256, t, snk);
        snk = warm_arr(c_b1,   32, t, snk);
        snk = warm_arr(c_w2, 1024, t, snk);
        snk = warm_arr(c_b2,    8, t, snk);
        snk = warm_arr(c_w3,   32, t, snk);
        snk = warm_arr(c_b3,    1, t, snk);
        snk = warm_arr(dD_w1, 512, t, snk);
        snk = warm_arr(dD_b1,  64, t, snk);
        snk = warm_arr(dD_w2, 2048, t, snk);
        snk = warm_arr(dD_b2,   8, t, snk);
        snk = warm_arr(dD_w3,  16, t, snk);
        snk = warm_arr(cC_w1, 192, t, snk);
        snk = warm_arr(cC_b1,  64, t, snk);
        snk = warm_arr(cC_w2, 2048, t, snk);
        snk = warm_arr(cC_b2,   8, t, snk);
        snk = warm_arr(cC_w3,  64, t, snk);
        snk = warm_arr(cC_b3,   2, t, snk);
        snk = warm_arr(cC_w4,  14, t, snk);
        asm volatile("" :: "v"(snk));
    }

    // ---- P0: feat (8 x 14)
    if (t < 112) {
        int l = t / 14, c = t - l * 14;
        float v;
        if      (c == 0) v = i_pos[0];
        else if (c == 1) v = j_pos[0];
        else if (c == 2) v = wtime_mu[l];
        else if (c == 3) v = wtime_sigma[l];
        else if (c == 4) v = wtime_max[l];
        else if (c == 5) v = waiting[l];
        else             v = phase[c - 6];
        feat[t] = v;
    }
    __syncthreads();

    // ---- P1: demand h1 (8x256), K=14. 1024 thr x 2 outs.
    for (int idx = t; idx < 2048; idx += 1024) {
        int l = idx >> 8, o = idx & 255;
        const float* w = d_w1 + o * 14;
        const float* f = feat + l * 14;
        float acc = d_b1[o];
#pragma unroll
        for (int c = 0; c < 14; ++c) acc = fmaf(f[c], w[c], acc);
        dh1[idx] = fmaxf(acc, 0.0f);
    }
    __syncthreads();

    // ---- P2: demand h2 (8x32), K=256. 1024 thr: 4-way K-split.
    {
        int l = t >> 7, o = (t >> 2) & 31, kq = t & 3;
        const float4* w = (const float4*)(d_w2 + o * 256) + kq * 16;
        const float4* h = (const float4*)(dh1 + l * 256) + kq * 16;
        float acc = 0.0f;
#pragma unroll
        for (int g = 0; g < 16; ++g) acc = dot4a(acc, h[g], w[g]);
        acc += __shfl_xor(acc, 1);
        acc += __shfl_xor(acc, 2);
        if (kq == 0) dh2[l * 32 + o] = fmaxf(acc + d_b2[o], 0.0f);
    }
    __syncthreads();

    // ---- P3: demand out (8x4), K=32. 128 thr: 4-way K-split.
    if (t < 128) {
        int u = t >> 2, kq = t & 3;
        int l = u >> 2, o = u & 3;
        const float4* w = (const float4*)(d_w3 + o * 32) + kq * 2;
        const float4* h = (const float4*)(dh2 + l * 32) + kq * 2;
        float acc = dot4a(dot4a(0.0f, h[0], w[0]), h[1], w[1]);
        acc += __shfl_xor(acc, 1);
        acc += __shfl_xor(acc, 2);
        if (kq == 0) dem[u] = acc + d_b3[o];
    }
    __syncthreads();

    // ---- P5: coupled h1 (8x128), K=8; PAIRS gather folded in.
    {
        int p = t >> 7, o = t & 127;
        int a0 = p & 3;
        int a1 = (p < 4) ? (4 + (p & 3)) : (4 + ((p & 3) ^ 1));
        float4 va = ((const float4*)dem)[a0];
        float4 vb = ((const float4*)dem)[a1];
        const float4* w = (const float4*)(c_w1 + o * 8);
        float acc = dot4a(dot4a(c_b1[o], va, w[0]), vb, w[1]);
        ch1[t] = fmaxf(acc, 0.0f);
    }
    __syncthreads();

    // ---- P6: coupled h2 (8x32), K=128. 1024 thr: 4-way K-split.
    {
        int l = t >> 7, o = (t >> 2) & 31, kq = t & 3;
        const float4* w = (const float4*)(c_w2 + o * 128) + kq * 8;
        const float4* h = (const float4*)(ch1 + l * 128) + kq * 8;
        float acc = 0.0f;
#pragma unroll
        for (int g = 0; g < 8; ++g) acc = dot4a(acc, h[g], w[g]);
        acc += __shfl_xor(acc, 1);
        acc += __shfl_xor(acc, 2);
        if (kq == 0) ch2[l * 32 + o] = fmaxf(acc + c_b2[o], 0.0f);
    }
    __syncthreads();

    // ---- P7: dp (8x4), K=32. 128 thr: 4-way K-split.
    if (t < 128) {
        int u = t >> 2, kq = t & 3;
        int l = u >> 2, o = u & 3;
        const float4* w = (const float4*)(c_w3 + o * 32) + kq * 2;
        const float4* h = (const float4*)(ch2 + l * 32) + kq * 2;
        float acc = dot4a(dot4a(0.0f, h[0], w[0]), h[1], w[1]);
        acc += __shfl_xor(acc, 1);
        acc += __shfl_xor(acc, 2);
        if (kq == 0) dp[u] = acc + c_b3[o];
    }
    __syncthreads();

    // ---- P8: conv_D h1 (256 x 56), K=8 from dp. Weight row hoisted.
    {
        const float4* dp4 = (const float4*)dp;
        int o = t & 255;
        const float4* wrow = (const float4*)(dD_w1 + o * 8);
        float4 w0 = wrow[0], w1 = wrow[1];
        float bias = dD_b1[o];
#pragma unroll
        for (int it = 0; it < 14; ++it) {
            int s = (t >> 8) + it * 4;
            int i = s / 7, k = s - i * 7;
            int j = k + (k >= i ? 1 : 0);
            float acc = dot4a(dot4a(bias, dp4[i], w0), dp4[j], w1);
            big[(s << 8) + (o ^ ((s & 7) << 2))] = fmaxf(acc, 0.0f);
        }
    }
    __syncthreads();

    // ---- P9: conv_D h2 (32 x 56), K=256, scalar-cache weights
    conv_h2_scalar(big, dD_w2, dD_b2, mid, t);
    __syncthreads();

    // ---- P10: conv_D h3 -> Hd (2 x 56), K=32. 448 thr: 4-way K-split.
    if (t < 448) {
        int u = t >> 2, kq = t & 3;
        int o = u / 56, s = u % 56;
        float acc = 0.0f;
#pragma unroll
        for (int cc = 0; cc < 8; ++cc) {
            int c = kq * 8 + cc;
            acc = fmaf(mid[c * 56 + s], dD_w3[o * 32 + c], acc);
        }
        acc += __shfl_xor(acc, 1);
        acc += __shfl_xor(acc, 2);
        if (kq == 0) Hd[o * 56 + s] = acc + dD_b3[o];
    }
    __syncthreads();

    // ---- P11: conv_C h1 (256 x 56): H_c channel 2 is zero -> 2 taps.
    {
        int o = t & 255;
        float w0 = cC_w1[o * 3], w1 = cC_w1[o * 3 + 1];
        float bias = cC_b1[o];
#pragma unroll
        for (int it = 0; it < 14; ++it) {
            int s = (t >> 8) + it * 4;
            float acc = fmaf(Hd[56 + s], w1, fmaf(Hd[s], w0, bias));
            big[(s << 8) + (o ^ ((s & 7) << 2))] = fmaxf(acc, 0.0f);
        }
    }
    __syncthreads();

    // ---- P12: conv_C h2 (32 x 56), K=256, scalar-cache weights
    conv_h2_scalar(big, cC_w2, cC_b2, mid, t);
    __syncthreads();

    // ---- P13: conv_C h3 (8 x 56), K=32, relu. 8 waves, scalar weights.
    {
        int wv = __builtin_amdgcn_readfirstlane(t >> 6);
        int s  = t & 63;
        if (wv < 8 && s < 56) {
            const float4* w = (const float4*)(cC_w3 + wv * 32);
            float acc = 0.0f;
#pragma unroll
            for (int g = 0; g < 8; ++g) {
                float4 m4;
                m4.x = mid[(g * 4 + 0) * 56 + s];
                m4.y = mid[(g * 4 + 1) * 56 + s];
                m4.z = mid[(g * 4 + 2) * 56 + s];
                m4.w = mid[(g * 4 + 3) * 56 + s];
                acc = dot4a(acc, m4, w[g]);
            }
            h3[wv * 56 + s] = fmaxf(acc + cC_b3[wv], 0.0f);
        }
    }
    __syncthreads();

    // ---- P14: final (1,7) conv: out[h] = sum_{c,w} cC_w4[c][w]*h3[c][h*7+w]+b4
    if (t < 64) {
        int h = t >> 3, c = t & 7;
        float p = 0.0f;
#pragma unroll
        for (int w = 0; w < 7; ++w)
            p = fmaf(cC_w4[c * 7 + w], h3[c * 56 + h * 7 + w], p);
#pragma unroll
        for (int off = 1; off < 8; off <<= 1) p += __shfl_xor(p, off);
        if (c == 0) out[h] = p + cC_b4[0];
    }
}

extern "C" void kernel_launch(void* const* d_in, const int* in_sizes, int n_in,
                              void* d_out, int out_size, void* d_ws, size_t ws_size,
                              hipStream_t stream) {
    (void)in_sizes; (void)n_in; (void)d_ws; (void)ws_size; (void)out_size;
    const float* a[33];
    for (int i = 0; i < 33; ++i) a[i] = (const float*)d_in[i];
    frap_kernel<<<dim3(1), dim3(1024), 0, stream>>>(
        a[0], a[1], a[2], a[3], a[4], a[5], a[6],
        a[7], a[8], a[9], a[10], a[11], a[12],
        a[13], a[14], a[15], a[16], a[17], a[18],
        a[19], a[20], a[21], a[22], a[23], a[24],
        a[25], a[26], a[27], a[28], a[29], a[30], a[31], a[32],
        (float*)d_out);
}

// Round 5
// 41.478 us; speedup vs baseline: 3.1641x; 1.0627x over previous
//
#include <hip/hip_runtime.h>

// FRAP forward — fully fused single-workgroup kernel (round 5).
// R4: 44.8us, no spills, VALU-issue ~11us -> ~30us exposed latency.
// Theory: early section P0-P7 = 9 lockstep barrier phases, each paying
// barrier drain + LDS turnaround + weight-fetch latency for ~0.3us work.
// R5: wave 0 runs the WHOLE early chain alone (intra-wave LDS ordering via
// s_waitcnt lgkmcnt(0)+sched_barrier, NO s_barrier), while waves 1..15 do
// the weight warm in parallel (wave0 demand loads MSHR-coalesce with warm).
// ONE __syncthreads joins before P8. Conv section unchanged from R4.
//
// LDS map (floats):
//   early (consumed before P8): feat16 @0(128, rows padded to 16)
//     dh1 @128(2048) dh2 @2176(256) dem @2432(32) ch1 @2560(1024)
//     ch2 @3584(256)
//   conv: big @0 (14336, swizzled [s][c])  mid @14336 (32x56 [o][s])
//         dp @16128(32)  Hd @16160(112)  h3 @0(448, after P12)
// Swizzle: (s,c) at big[s*256 + ((c>>2)^(s&7))*4 + (c&3)].

#define DEV __device__ __forceinline__

// Intra-wave LDS producer->consumer fence (rule #18: lgkmcnt + sched_barrier).
#define WAVE_SYNC() do { \
    asm volatile("s_waitcnt lgkmcnt(0)" ::: "memory"); \
    __builtin_amdgcn_sched_barrier(0); \
} while (0)

DEV float dot4a(float acc, float4 a, float4 b) {
    acc = fmaf(a.x, b.x, acc);
    acc = fmaf(a.y, b.y, acc);
    acc = fmaf(a.z, b.z, acc);
    acc = fmaf(a.w, b.w, acc);
    return acc;
}

// Coalesced cache-warm over 960 threads (waves 1..15), id = t-64.
DEV float warm_arr(const float* __restrict__ p, int n4, int id, float sink) {
    const float4* p4 = (const float4*)p;
    for (int i = id; i < n4; i += 960) {
        float4 v = p4[i];
        sink += v.x + v.y + v.z + v.w;
    }
    return sink;
}

// conv h2: big (swizzled [s][256]) -> relu(W(32x256)@.) -> mid[o*56+s].
// 8 waves; wave wv owns channels 4wv..4wv+3 (uniform -> s_load weights).
DEV void conv_h2_scalar(const float* __restrict__ big, const float* __restrict__ w2g,
                        const float* __restrict__ b2g, float* __restrict__ mid, int t)
{
    int wv = __builtin_amdgcn_readfirstlane(t >> 6);
    int s  = t & 63;
    if (wv < 8 && s < 56) {
        const float4* hrow = (const float4*)(big + (s << 8));
        int sw = s & 7;
        const float4* w0 = (const float4*)(w2g + (wv * 4 + 0) * 256);
        const float4* w1 = (const float4*)(w2g + (wv * 4 + 1) * 256);
        const float4* w2 = (const float4*)(w2g + (wv * 4 + 2) * 256);
        const float4* w3 = (const float4*)(w2g + (wv * 4 + 3) * 256);
        float a0 = 0.0f, a1 = 0.0f, a2 = 0.0f, a3 = 0.0f;
#pragma unroll 8
        for (int g = 0; g < 64; ++g) {
            float4 v = hrow[g ^ sw];
            a0 = dot4a(a0, v, w0[g]);
            a1 = dot4a(a1, v, w1[g]);
            a2 = dot4a(a2, v, w2[g]);
            a3 = dot4a(a3, v, w3[g]);
        }
        mid[(wv * 4 + 0) * 56 + s] = fmaxf(a0 + b2g[wv * 4 + 0], 0.0f);
        mid[(wv * 4 + 1) * 56 + s] = fmaxf(a1 + b2g[wv * 4 + 1], 0.0f);
        mid[(wv * 4 + 2) * 56 + s] = fmaxf(a2 + b2g[wv * 4 + 2], 0.0f);
        mid[(wv * 4 + 3) * 56 + s] = fmaxf(a3 + b2g[wv * 4 + 3], 0.0f);
    }
}

__global__ __launch_bounds__(1024, 1) void frap_kernel(
    const float* __restrict__ waiting, const float* __restrict__ phase,
    const float* __restrict__ wtime_mu, const float* __restrict__ wtime_sigma,
    const float* __restrict__ wtime_max,
    const float* __restrict__ i_pos, const float* __restrict__ j_pos,
    const float* __restrict__ d_w1, const float* __restrict__ d_b1,
    const float* __restrict__ d_w2, const float* __restrict__ d_b2,
    const float* __restrict__ d_w3, const float* __restrict__ d_b3,
    const float* __restrict__ c_w1, const float* __restrict__ c_b1,
    const float* __restrict__ c_w2, const float* __restrict__ c_b2,
    const float* __restrict__ c_w3, const float* __restrict__ c_b3,
    const float* __restrict__ dD_w1, const float* __restrict__ dD_b1,
    const float* __restrict__ dD_w2, const float* __restrict__ dD_b2,
    const float* __restrict__ dD_w3, const float* __restrict__ dD_b3,
    const float* __restrict__ cC_w1, const float* __restrict__ cC_b1,
    const float* __restrict__ cC_w2, const float* __restrict__ cC_b2,
    const float* __restrict__ cC_w3, const float* __restrict__ cC_b3,
    const float* __restrict__ cC_w4, const float* __restrict__ cC_b4,
    float* __restrict__ out)
{
    __shared__ __align__(16) float sm[16384];   // 64 KB
    const int t  = threadIdx.x;
    const int wv = t >> 6;
    const int ln = t & 63;

    float* feat16 = sm;        // 128 (8 rows x 16, cols 14/15 = 0)
    float* dh1  = sm + 128;    // 2048
    float* dh2  = sm + 2176;   // 256
    float* dem  = sm + 2432;   // 32
    float* ch1  = sm + 2560;   // 1024
    float* ch2  = sm + 3584;   // 256
    float* big  = sm;          // 14336 (swizzled [s][c])
    float* mid  = sm + 14336;  // 1792  [o][s]
    float* dp   = sm + 16128;  // 32
    float* Hd   = sm + 16160;  // 112
    float* h3   = sm;          // 448 (reuses big after P12)

    if (wv == 0) {
        // ================= wave-solo early chain (no workgroup barriers) ====
        // P0: feat16
        for (int rep = 0; rep < 2; ++rep) {
            int idx = rep * 64 + ln;            // 0..127
            int l = idx >> 4, c = idx & 15;
            float v = 0.0f;
            if      (c == 0) v = i_pos[0];
            else if (c == 1) v = j_pos[0];
            else if (c == 2) v = wtime_mu[l];
            else if (c == 3) v = wtime_sigma[l];
            else if (c == 4) v = wtime_max[l];
            else if (c == 5) v = waiting[l];
            else if (c < 14) v = phase[c - 6];
            feat16[idx] = v;
        }
        WAVE_SYNC();

        // P1: dh1[l*256+o] = relu(feat @ d_w1^T), K=14. lane owns o=q*64+ln.
        for (int q = 0; q < 4; ++q) {
            int o = q * 64 + ln;
            const float* w = d_w1 + o * 14;
            float w0 = w[0], w1 = w[1], w2 = w[2], w3 = w[3], w4 = w[4];
            float w5 = w[5], w6 = w[6], w7 = w[7], w8 = w[8], w9 = w[9];
            float wa = w[10], wb = w[11], wc = w[12], wd = w[13];
            float bias = d_b1[o];
#pragma unroll
            for (int l = 0; l < 8; ++l) {
                const float4* f4 = (const float4*)(feat16 + l * 16);
                float4 f0 = f4[0], f1 = f4[1], f2 = f4[2], f3 = f4[3];
                float acc = bias;
                acc = fmaf(f0.x, w0, acc); acc = fmaf(f0.y, w1, acc);
                acc = fmaf(f0.z, w2, acc); acc = fmaf(f0.w, w3, acc);
                acc = fmaf(f1.x, w4, acc); acc = fmaf(f1.y, w5, acc);
                acc = fmaf(f1.z, w6, acc); acc = fmaf(f1.w, w7, acc);
                acc = fmaf(f2.x, w8, acc); acc = fmaf(f2.y, w9, acc);
                acc = fmaf(f2.z, wa, acc); acc = fmaf(f2.w, wb, acc);
                acc = fmaf(f3.x, wc, acc); acc = fmaf(f3.y, wd, acc);
                dh1[l * 256 + o] = fmaxf(acc, 0.0f);
            }
        }
        WAVE_SYNC();

        // P2: dh2[l*32+o], K=256. lane = (lh, o): 4 l's per lane.
        {
            int o = ln & 31, lh = ln >> 5;
            float acc0 = 0.0f, acc1 = 0.0f, acc2 = 0.0f, acc3 = 0.0f;
            const float4* w4p = (const float4*)(d_w2 + o * 256);
#pragma unroll 4
            for (int cb = 0; cb < 64; ++cb) {
                float4 w = w4p[cb];
                float4 h0 = *(const float4*)(dh1 + (lh * 4 + 0) * 256 + cb * 4);
                float4 h1 = *(const float4*)(dh1 + (lh * 4 + 1) * 256 + cb * 4);
                float4 h2 = *(const float4*)(dh1 + (lh * 4 + 2) * 256 + cb * 4);
                float4 h3v = *(const float4*)(dh1 + (lh * 4 + 3) * 256 + cb * 4);
                acc0 = dot4a(acc0, h0, w);
                acc1 = dot4a(acc1, h1, w);
                acc2 = dot4a(acc2, h2, w);
                acc3 = dot4a(acc3, h3v, w);
            }
            float b = d_b2[o];
            dh2[(lh * 4 + 0) * 32 + o] = fmaxf(acc0 + b, 0.0f);
            dh2[(lh * 4 + 1) * 32 + o] = fmaxf(acc1 + b, 0.0f);
            dh2[(lh * 4 + 2) * 32 + o] = fmaxf(acc2 + b, 0.0f);
            dh2[(lh * 4 + 3) * 32 + o] = fmaxf(acc3 + b, 0.0f);
        }
        WAVE_SYNC();

        // P3: dem (8x4), K=32. lanes 0..31.
        if (ln < 32) {
            int l = ln >> 2, o = ln & 3;
            const float4* w = (const float4*)(d_w3 + o * 32);
            const float4* h = (const float4*)(dh2 + l * 32);
            float acc = d_b3[o];
#pragma unroll
            for (int g = 0; g < 8; ++g) acc = dot4a(acc, h[g], w[g]);
            dem[ln] = acc;
        }
        WAVE_SYNC();

        // P5: ch1[p*128+o], K=8, PAIRS folded. lane owns o=rep*64+ln.
        for (int rep = 0; rep < 2; ++rep) {
            int o = rep * 64 + ln;
            const float4* w = (const float4*)(c_w1 + o * 8);
            float4 w0 = w[0], w1 = w[1];
            float bias = c_b1[o];
#pragma unroll
            for (int p = 0; p < 8; ++p) {
                int a0 = p & 3;
                int a1 = (p < 4) ? (4 + (p & 3)) : (4 + ((p & 3) ^ 1));
                float4 va = *(const float4*)(dem + a0 * 4);
                float4 vb = *(const float4*)(dem + a1 * 4);
                float acc = dot4a(dot4a(bias, va, w0), vb, w1);
                ch1[p * 128 + o] = fmaxf(acc, 0.0f);
            }
        }
        WAVE_SYNC();

        // P6: ch2[l*32+o], K=128. lane = (lh, o).
        {
            int o = ln & 31, lh = ln >> 5;
            float acc0 = 0.0f, acc1 = 0.0f, acc2 = 0.0f, acc3 = 0.0f;
            const float4* w4p = (const float4*)(c_w2 + o * 128);
#pragma unroll 4
            for (int cb = 0; cb < 32; ++cb) {
                float4 w = w4p[cb];
                float4 h0 = *(const float4*)(ch1 + (lh * 4 + 0) * 128 + cb * 4);
                float4 h1 = *(const float4*)(ch1 + (lh * 4 + 1) * 128 + cb * 4);
                float4 h2 = *(const float4*)(ch1 + (lh * 4 + 2) * 128 + cb * 4);
                float4 h3v = *(const float4*)(ch1 + (lh * 4 + 3) * 128 + cb * 4);
                acc0 = dot4a(acc0, h0, w);
                acc1 = dot4a(acc1, h1, w);
                acc2 = dot4a(acc2, h2, w);
                acc3 = dot4a(acc3, h3v, w);
            }
            float b = c_b2[o];
            ch2[(lh * 4 + 0) * 32 + o] = fmaxf(acc0 + b, 0.0f);
            ch2[(lh * 4 + 1) * 32 + o] = fmaxf(acc1 + b, 0.0f);
            ch2[(lh * 4 + 2) * 32 + o] = fmaxf(acc2 + b, 0.0f);
            ch2[(lh * 4 + 3) * 32 + o] = fmaxf(acc3 + b, 0.0f);
        }
        WAVE_SYNC();

        // P7: dp (8x4), K=32. lanes 0..31.
        if (ln < 32) {
            int l = ln >> 2, o = ln & 3;
            const float4* w = (const float4*)(c_w3 + o * 32);
            const float4* h = (const float4*)(ch2 + l * 32);
            float acc = c_b3[o];
#pragma unroll
            for (int g = 0; g < 8; ++g) acc = dot4a(acc, h[g], w[g]);
            dp[ln] = acc;
        }
        // dp becomes visible to all waves via the join __syncthreads below.
    } else {
        // ================= waves 1..15: parallel weight warm =================
        int id = t - 64;    // 0..959
        float snk = 0.0f;
        snk = warm_arr(d_w1,  896, id, snk);
        snk = warm_arr(d_b1,   64, id, snk);
        snk = warm_arr(d_w2, 2048, id, snk);
        snk = warm_arr(d_b2,    8, id, snk);
        snk = warm_arr(d_w3,   32, id, snk);
        snk = warm_arr(d_b3,    1, id, snk);
        snk = warm_arr(c_w1,  256, id, snk);
        snk = warm_arr(c_b1,   32, id, snk);
        snk = warm_arr(c_w2, 1024, id, snk);
        snk = warm_arr(c_b2,    8, id, snk);
        snk = warm_arr(c_w3,   32, id, snk);
        snk = warm_arr(c_b3,    1, id, snk);
        snk = warm_arr(dD_w1, 512, id, snk);
        snk = warm_arr(dD_b1,  64, id, snk);
        snk = warm_arr(dD_w2, 2048, id, snk);
        snk = warm_arr(dD_b2,   8, id, snk);
        snk = warm_arr(dD_w3,  16, id, snk);
        snk = warm_arr(cC_w1, 192, id, snk);
        snk = warm_arr(cC_b1,  64, id, snk);
        snk = warm_arr(cC_w2, 2048, id, snk);
        snk = warm_arr(cC_b2,   8, id, snk);
        snk = warm_arr(cC_w3,  64, id, snk);
        snk = warm_arr(cC_b3,   2, id, snk);
        snk = warm_arr(cC_w4,  14, id, snk);
        asm volatile("" :: "v"(snk));
    }
    __syncthreads();   // single join: dp ready, weights warm

    // ================= conv section (unchanged from R4) =====================
    // P8: conv_D h1 (256 x 56), K=8 from dp.
    {
        const float4* dp4 = (const float4*)dp;
        int o = t & 255;
        const float4* wrow = (const float4*)(dD_w1 + o * 8);
        float4 w0 = wrow[0], w1 = wrow[1];
        float bias = dD_b1[o];
#pragma unroll
        for (int it = 0; it < 14; ++it) {
            int s = (t >> 8) + it * 4;
            int i = s / 7, k = s - i * 7;
            int j = k + (k >= i ? 1 : 0);
            float acc = dot4a(dot4a(bias, dp4[i], w0), dp4[j], w1);
            big[(s << 8) + (o ^ ((s & 7) << 2))] = fmaxf(acc, 0.0f);
        }
    }
    __syncthreads();

    // P9: conv_D h2 (32 x 56), K=256, scalar-cache weights
    conv_h2_scalar(big, dD_w2, dD_b2, mid, t);
    __syncthreads();

    // P10: conv_D h3 -> Hd (2 x 56), K=32. 448 thr: 4-way K-split.
    if (t < 448) {
        int u = t >> 2, kq = t & 3;
        int o = u / 56, s = u % 56;
        float acc = 0.0f;
#pragma unroll
        for (int cc = 0; cc < 8; ++cc) {
            int c = kq * 8 + cc;
            acc = fmaf(mid[c * 56 + s], dD_w3[o * 32 + c], acc);
        }
        acc += __shfl_xor(acc, 1);
        acc += __shfl_xor(acc, 2);
        if (kq == 0) Hd[o * 56 + s] = acc + dD_b3[o];
    }
    __syncthreads();

    // P11: conv_C h1 (256 x 56): H_c channel 2 is zero -> 2 taps.
    {
        int o = t & 255;
        float w0 = cC_w1[o * 3], w1 = cC_w1[o * 3 + 1];
        float bias = cC_b1[o];
#pragma unroll
        for (int it = 0; it < 14; ++it) {
            int s = (t >> 8) + it * 4;
            float acc = fmaf(Hd[56 + s], w1, fmaf(Hd[s], w0, bias));
            big[(s << 8) + (o ^ ((s & 7) << 2))] = fmaxf(acc, 0.0f);
        }
    }
    __syncthreads();

    // P12: conv_C h2 (32 x 56), K=256, scalar-cache weights
    conv_h2_scalar(big, cC_w2, cC_b2, mid, t);
    __syncthreads();

    // P13: conv_C h3 (8 x 56), K=32, relu. 8 waves, scalar weights.
    {
        int wv8 = __builtin_amdgcn_readfirstlane(t >> 6);
        int s  = t & 63;
        if (wv8 < 8 && s < 56) {
            const float4* w = (const float4*)(cC_w3 + wv8 * 32);
            float acc = 0.0f;
#pragma unroll
            for (int g = 0; g < 8; ++g) {
                float4 m4;
                m4.x = mid[(g * 4 + 0) * 56 + s];
                m4.y = mid[(g * 4 + 1) * 56 + s];
                m4.z = mid[(g * 4 + 2) * 56 + s];
                m4.w = mid[(g * 4 + 3) * 56 + s];
                acc = dot4a(acc, m4, w[g]);
            }
            h3[wv8 * 56 + s] = fmaxf(acc + cC_b3[wv8], 0.0f);
        }
    }
    __syncthreads();

    // P14: final (1,7) conv: out[h] = sum_{c,w} cC_w4[c][w]*h3[c][h*7+w]+b4
    if (t < 64) {
        int h = t >> 3, c = t & 7;
        float p = 0.0f;
#pragma unroll
        for (int w = 0; w < 7; ++w)
            p = fmaf(cC_w4[c * 7 + w], h3[c * 56 + h * 7 + w], p);
#pragma unroll
        for (int off = 1; off < 8; off <<= 1) p += __shfl_xor(p, off);
        if (c == 0) out[h] = p + cC_b4[0];
    }
}

extern "C" void kernel_launch(void* const* d_in, const int* in_sizes, int n_in,
                              void* d_out, int out_size, void* d_ws, size_t ws_size,
                              hipStream_t stream) {
    (void)in_sizes; (void)n_in; (void)d_ws; (void)ws_size; (void)out_size;
    const float* a[33];
    for (int i = 0; i < 33; ++i) a[i] = (const float*)d_in[i];
    frap_kernel<<<dim3(1), dim3(1024), 0, stream>>>(
        a[0], a[1], a[2], a[3], a[4], a[5], a[6],
        a[7], a[8], a[9], a[10], a[11], a[12],
        a[13], a[14], a[15], a[16], a[17], a[18],
        a[19], a[20], a[21], a[22], a[23], a[24],
        a[25], a[26], a[27], a[28], a[29], a[30], a[31], a[32],
        (float*)d_out);
}

// Round 6
// 27.878 us; speedup vs baseline: 4.7077x; 1.4879x over previous
//
#include <hip/hip_runtime.h>

// FRAP forward — round 6: redundant-compute multi-CU split.
// R5 lesson: 1024-thr block caps VGPR at 64 -> wave0 chain spilled (WRITE 30KB).
// Structure: grid 4 x 512. After dp (P7), all conv phases are pointwise in the
// 56 spatial positions; final conv needs only its own row. So each WG owns
// 14 positions (2 output rows). Instead of broadcasting dp, EVERY WG's wave 0
// recomputes the tiny early chain (deterministic -> identical dp) while waves
// 1-7 warm weights into the local XCD L2. Zero cross-WG communication.
//
// Per-WG LDS (floats, sm[4096] = 16KB):
//   early (dead after join): feat16 @0(128) dh1 @128(2048) dh2 @2176(256)
//     dem @2432(32) ch1 @2464(1024) ch2 @3488(256)
//   conv: big @0 (14x256 swizzled [sl][c])  mid @3584 (32x14 [o][sl])
//         dp @4032(32)  Hd @4064(28, [2][14])  h3 @0(112, after P12)
// Swizzle: (sl,c) at big[sl*256 + ((c>>2)^(sl&7))*4 + (c&3)].

#define DEV __device__ __forceinline__

// Intra-wave LDS producer->consumer fence (rule #18).
#define WAVE_SYNC() do { \
    asm volatile("s_waitcnt lgkmcnt(0)" ::: "memory"); \
    __builtin_amdgcn_sched_barrier(0); \
} while (0)

DEV float dot4a(float acc, float4 a, float4 b) {
    acc = fmaf(a.x, b.x, acc);
    acc = fmaf(a.y, b.y, acc);
    acc = fmaf(a.z, b.z, acc);
    acc = fmaf(a.w, b.w, acc);
    return acc;
}

// Coalesced cache-warm over waves 1..7 (448 threads), id = t-64.
DEV float warm_arr(const float* __restrict__ p, int n4, int id, float sink) {
    const float4* p4 = (const float4*)p;
    for (int i = id; i < n4; i += 448) {
        float4 v = p4[i];
        sink += v.x + v.y + v.z + v.w;
    }
    return sink;
}

// conv h2: big (swizzled [sl][256], sl<14) -> relu(W(32x256)@.) -> mid[ch*14+sl]
// 8 waves; lane = (sub-ch = ln>>4, sl = ln&15). Full K per lane, 4 accs,
// per-lane vector weight loads (4 broadcast addrs/instr). No reduce needed.
DEV void conv_h2_vec(const float* __restrict__ big, const float* __restrict__ w2g,
                     const float* __restrict__ b2g, float* __restrict__ mid, int t)
{
    int wv = t >> 6;             // 0..7
    int ln = t & 63;
    int sl = ln & 15;            // s_local 0..13 (14,15 idle)
    int ch = wv * 4 + (ln >> 4); // 0..31
    if (sl < 14) {
        const float4* wp = (const float4*)(w2g + ch * 256);
        const float* hrow = big + (sl << 8);
        int sw = sl & 7;
        float a0 = 0.0f, a1 = 0.0f, a2 = 0.0f, a3 = 0.0f;
#pragma unroll 4
        for (int g = 0; g < 64; g += 4) {
            float4 w0 = wp[g + 0], w1 = wp[g + 1], w2 = wp[g + 2], w3 = wp[g + 3];
            float4 h0 = *(const float4*)(hrow + (((g + 0) ^ sw) << 2));
            float4 h1 = *(const float4*)(hrow + (((g + 1) ^ sw) << 2));
            float4 h2 = *(const float4*)(hrow + (((g + 2) ^ sw) << 2));
            float4 h3v = *(const float4*)(hrow + (((g + 3) ^ sw) << 2));
            a0 = dot4a(a0, h0, w0);
            a1 = dot4a(a1, h1, w1);
            a2 = dot4a(a2, h2, w2);
            a3 = dot4a(a3, h3v, w3);
        }
        float r = ((a0 + a1) + (a2 + a3)) + b2g[ch];
        mid[ch * 14 + sl] = fmaxf(r, 0.0f);
    }
}

__global__ __launch_bounds__(512, 1) void frap_kernel(
    const float* __restrict__ waiting, const float* __restrict__ phase,
    const float* __restrict__ wtime_mu, const float* __restrict__ wtime_sigma,
    const float* __restrict__ wtime_max,
    const float* __restrict__ i_pos, const float* __restrict__ j_pos,
    const float* __restrict__ d_w1, const float* __restrict__ d_b1,
    const float* __restrict__ d_w2, const float* __restrict__ d_b2,
    const float* __restrict__ d_w3, const float* __restrict__ d_b3,
    const float* __restrict__ c_w1, const float* __restrict__ c_b1,
    const float* __restrict__ c_w2, const float* __restrict__ c_b2,
    const float* __restrict__ c_w3, const float* __restrict__ c_b3,
    const float* __restrict__ dD_w1, const float* __restrict__ dD_b1,
    const float* __restrict__ dD_w2, const float* __restrict__ dD_b2,
    const float* __restrict__ dD_w3, const float* __restrict__ dD_b3,
    const float* __restrict__ cC_w1, const float* __restrict__ cC_b1,
    const float* __restrict__ cC_w2, const float* __restrict__ cC_b2,
    const float* __restrict__ cC_w3, const float* __restrict__ cC_b3,
    const float* __restrict__ cC_w4, const float* __restrict__ cC_b4,
    float* __restrict__ out)
{
    __shared__ __align__(16) float sm[4096];   // 16 KB
    const int t  = threadIdx.x;
    const int wg = blockIdx.x;                 // 0..3, owns s = wg*14 .. +13
    const int ln = t & 63;

    float* feat16 = sm;        // 128 (8 rows x 16, cols 14/15 = 0)
    float* dh1  = sm + 128;    // 2048
    float* dh2  = sm + 2176;   // 256
    float* dem  = sm + 2432;   // 32
    float* ch1  = sm + 2464;   // 1024
    float* ch2  = sm + 3488;   // 256
    float* big  = sm;          // 3584 (swizzled [sl][256])
    float* mid  = sm + 3584;   // 448  [o][sl]
    float* dp   = sm + 4032;   // 32
    float* Hd   = sm + 4064;   // 28   [2][14]
    float* h3   = sm;          // 112 (reuses big after P12)

    if (t < 64) {
        // ========== wave-solo early chain (identical in every WG) ==========
        // P0: feat16
        for (int rep = 0; rep < 2; ++rep) {
            int idx = rep * 64 + ln;
            int l = idx >> 4, c = idx & 15;
            float v = 0.0f;
            if      (c == 0) v = i_pos[0];
            else if (c == 1) v = j_pos[0];
            else if (c == 2) v = wtime_mu[l];
            else if (c == 3) v = wtime_sigma[l];
            else if (c == 4) v = wtime_max[l];
            else if (c == 5) v = waiting[l];
            else if (c < 14) v = phase[c - 6];
            feat16[idx] = v;
        }
        WAVE_SYNC();

        // P1: dh1[l*256+o] = relu(feat @ d_w1^T), K=14.
        for (int q = 0; q < 4; ++q) {
            int o = q * 64 + ln;
            const float* w = d_w1 + o * 14;
            float w0 = w[0], w1 = w[1], w2 = w[2], w3 = w[3], w4 = w[4];
            float w5 = w[5], w6 = w[6], w7 = w[7], w8 = w[8], w9 = w[9];
            float wa = w[10], wb = w[11], wc = w[12], wd = w[13];
            float bias = d_b1[o];
#pragma unroll
            for (int l = 0; l < 8; ++l) {
                const float4* f4 = (const float4*)(feat16 + l * 16);
                float4 f0 = f4[0], f1 = f4[1], f2 = f4[2], f3 = f4[3];
                float acc = bias;
                acc = fmaf(f0.x, w0, acc); acc = fmaf(f0.y, w1, acc);
                acc = fmaf(f0.z, w2, acc); acc = fmaf(f0.w, w3, acc);
                acc = fmaf(f1.x, w4, acc); acc = fmaf(f1.y, w5, acc);
                acc = fmaf(f1.z, w6, acc); acc = fmaf(f1.w, w7, acc);
                acc = fmaf(f2.x, w8, acc); acc = fmaf(f2.y, w9, acc);
                acc = fmaf(f2.z, wa, acc); acc = fmaf(f2.w, wb, acc);
                acc = fmaf(f3.x, wc, acc); acc = fmaf(f3.y, wd, acc);
                dh1[l * 256 + o] = fmaxf(acc, 0.0f);
            }
        }
        WAVE_SYNC();

        // P2: dh2[l*32+o], K=256. lane = (lh, o): 4 rows per lane.
        {
            int o = ln & 31, lh = ln >> 5;
            float acc0 = 0.0f, acc1 = 0.0f, acc2 = 0.0f, acc3 = 0.0f;
            const float4* w4p = (const float4*)(d_w2 + o * 256);
#pragma unroll 4
            for (int cb = 0; cb < 64; ++cb) {
                float4 w = w4p[cb];
                float4 h0 = *(const float4*)(dh1 + (lh * 4 + 0) * 256 + cb * 4);
                float4 h1 = *(const float4*)(dh1 + (lh * 4 + 1) * 256 + cb * 4);
                float4 h2 = *(const float4*)(dh1 + (lh * 4 + 2) * 256 + cb * 4);
                float4 h3v = *(const float4*)(dh1 + (lh * 4 + 3) * 256 + cb * 4);
                acc0 = dot4a(acc0, h0, w);
                acc1 = dot4a(acc1, h1, w);
                acc2 = dot4a(acc2, h2, w);
                acc3 = dot4a(acc3, h3v, w);
            }
            float b = d_b2[o];
            dh2[(lh * 4 + 0) * 32 + o] = fmaxf(acc0 + b, 0.0f);
            dh2[(lh * 4 + 1) * 32 + o] = fmaxf(acc1 + b, 0.0f);
            dh2[(lh * 4 + 2) * 32 + o] = fmaxf(acc2 + b, 0.0f);
            dh2[(lh * 4 + 3) * 32 + o] = fmaxf(acc3 + b, 0.0f);
        }
        WAVE_SYNC();

        // P3: dem (8x4), K=32.
        if (ln < 32) {
            int l = ln >> 2, o = ln & 3;
            const float4* w = (const float4*)(d_w3 + o * 32);
            const float4* h = (const float4*)(dh2 + l * 32);
            float acc = d_b3[o];
#pragma unroll
            for (int g = 0; g < 8; ++g) acc = dot4a(acc, h[g], w[g]);
            dem[ln] = acc;
        }
        WAVE_SYNC();

        // P5: ch1[p*128+o], K=8, PAIRS folded.
        for (int rep = 0; rep < 2; ++rep) {
            int o = rep * 64 + ln;
            const float4* w = (const float4*)(c_w1 + o * 8);
            float4 w0 = w[0], w1 = w[1];
            float bias = c_b1[o];
#pragma unroll
            for (int p = 0; p < 8; ++p) {
                int a0 = p & 3;
                int a1 = (p < 4) ? (4 + (p & 3)) : (4 + ((p & 3) ^ 1));
                float4 va = *(const float4*)(dem + a0 * 4);
                float4 vb = *(const float4*)(dem + a1 * 4);
                float acc = dot4a(dot4a(bias, va, w0), vb, w1);
                ch1[p * 128 + o] = fmaxf(acc, 0.0f);
            }
        }
        WAVE_SYNC();

        // P6: ch2[l*32+o], K=128.
        {
            int o = ln & 31, lh = ln >> 5;
            float acc0 = 0.0f, acc1 = 0.0f, acc2 = 0.0f, acc3 = 0.0f;
            const float4* w4p = (const float4*)(c_w2 + o * 128);
#pragma unroll 4
            for (int cb = 0; cb < 32; ++cb) {
                float4 w = w4p[cb];
                float4 h0 = *(const float4*)(ch1 + (lh * 4 + 0) * 128 + cb * 4);
                float4 h1 = *(const float4*)(ch1 + (lh * 4 + 1) * 128 + cb * 4);
                float4 h2 = *(const float4*)(ch1 + (lh * 4 + 2) * 128 + cb * 4);
                float4 h3v = *(const float4*)(ch1 + (lh * 4 + 3) * 128 + cb * 4);
                acc0 = dot4a(acc0, h0, w);
                acc1 = dot4a(acc1, h1, w);
                acc2 = dot4a(acc2, h2, w);
                acc3 = dot4a(acc3, h3v, w);
            }
            float b = c_b2[o];
            ch2[(lh * 4 + 0) * 32 + o] = fmaxf(acc0 + b, 0.0f);
            ch2[(lh * 4 + 1) * 32 + o] = fmaxf(acc1 + b, 0.0f);
            ch2[(lh * 4 + 2) * 32 + o] = fmaxf(acc2 + b, 0.0f);
            ch2[(lh * 4 + 3) * 32 + o] = fmaxf(acc3 + b, 0.0f);
        }
        WAVE_SYNC();

        // P7: dp (8x4), K=32.
        if (ln < 32) {
            int l = ln >> 2, o = ln & 3;
            const float4* w = (const float4*)(c_w3 + o * 32);
            const float4* h = (const float4*)(ch2 + l * 32);
            float acc = c_b3[o];
#pragma unroll
            for (int g = 0; g < 8; ++g) acc = dot4a(acc, h[g], w[g]);
            dp[ln] = acc;
        }
    } else {
        // ========== waves 1..7: warm full weight set into local XCD L2 ======
        int id = t - 64;    // 0..447
        float snk = 0.0f;
        snk = warm_arr(d_w1,  896, id, snk);
        snk = warm_arr(d_b1,   64, id, snk);
        snk = warm_arr(d_w2, 2048, id, snk);
        snk = warm_arr(d_b2,    8, id, snk);
        snk = warm_arr(d_w3,   32, id, snk);
        snk = warm_arr(d_b3,    1, id, snk);
        snk = warm_arr(c_w1,  256, id, snk);
        snk = warm_arr(c_b1,   32, id, snk);
        snk = warm_arr(c_w2, 1024, id, snk);
        snk = warm_arr(c_b2,    8, id, snk);
        snk = warm_arr(c_w3,   32, id, snk);
        snk = warm_arr(c_b3,    1, id, snk);
        snk = warm_arr(dD_w1, 512, id, snk);
        snk = warm_arr(dD_b1,  64, id, snk);
        snk = warm_arr(dD_w2, 2048, id, snk);
        snk = warm_arr(dD_b2,   8, id, snk);
        snk = warm_arr(dD_w3,  16, id, snk);
        snk = warm_arr(cC_w1, 192, id, snk);
        snk = warm_arr(cC_b1,  64, id, snk);
        snk = warm_arr(cC_w2, 2048, id, snk);
        snk = warm_arr(cC_b2,   8, id, snk);
        snk = warm_arr(cC_w3,  64, id, snk);
        snk = warm_arr(cC_b3,   2, id, snk);
        snk = warm_arr(cC_w4,  14, id, snk);
        asm volatile("" :: "v"(snk));
    }
    __syncthreads();   // join: dp ready, weights warm

    // ============ conv section on s_local 0..13 (global s = wg*14+sl) ======
    // P8: conv_D h1 (256 ch x 14 sl), K=8 from dp.
    {
        const float4* dp4 = (const float4*)dp;
        int o = t & 255;
        const float4* wrow = (const float4*)(dD_w1 + o * 8);
        float4 w0 = wrow[0], w1 = wrow[1];
        float bias = dD_b1[o];
#pragma unroll
        for (int it = 0; it < 7; ++it) {
            int sl = (t >> 8) + it * 2;
            int sg = wg * 14 + sl;
            int i = sg / 7, k = sg - i * 7;
            int j = k + (k >= i ? 1 : 0);
            float acc = dot4a(dot4a(bias, dp4[i], w0), dp4[j], w1);
            big[(sl << 8) + (o ^ ((sl & 7) << 2))] = fmaxf(acc, 0.0f);
        }
    }
    __syncthreads();

    // P9: conv_D h2 (32 x 14), K=256
    conv_h2_vec(big, dD_w2, dD_b2, mid, t);
    __syncthreads();

    // P10: conv_D h3 -> Hd (2 x 14), K=32. 4-way K-split.
    if (t < 112) {
        int kq = t & 3, u = t >> 2;          // u 0..27
        int o = (u >= 14) ? 1 : 0;
        int s = u - o * 14;
        float acc = 0.0f;
#pragma unroll
        for (int cc = 0; cc < 8; ++cc) {
            int c = kq * 8 + cc;
            acc = fmaf(mid[c * 14 + s], dD_w3[o * 32 + c], acc);
        }
        acc += __shfl_xor(acc, 1);
        acc += __shfl_xor(acc, 2);
        if (kq == 0) Hd[o * 14 + s] = acc + dD_b3[o];
    }
    __syncthreads();

    // P11: conv_C h1 (256 x 14): H_c channel 2 is zero -> 2 taps.
    {
        int o = t & 255;
        float w0 = cC_w1[o * 3], w1 = cC_w1[o * 3 + 1];
        float bias = cC_b1[o];
#pragma unroll
        for (int it = 0; it < 7; ++it) {
            int sl = (t >> 8) + it * 2;
            float acc = fmaf(Hd[14 + sl], w1, fmaf(Hd[sl], w0, bias));
            big[(sl << 8) + (o ^ ((sl & 7) << 2))] = fmaxf(acc, 0.0f);
        }
    }
    __syncthreads();

    // P12: conv_C h2 (32 x 14), K=256
    conv_h2_vec(big, cC_w2, cC_b2, mid, t);
    __syncthreads();

    // P13: conv_C h3 (8 x 14), K=32, relu -> h3 (reuses big region).
    if (t < 448) {
        int kq = t & 3, u = t >> 2;          // u 0..111
        int o = u & 7, s = u >> 3;           // s 0..13
        float acc = 0.0f;
#pragma unroll
        for (int cc = 0; cc < 8; ++cc) {
            int c = kq * 8 + cc;
            acc = fmaf(mid[c * 14 + s], cC_w3[o * 32 + c], acc);
        }
        acc += __shfl_xor(acc, 1);
        acc += __shfl_xor(acc, 2);
        if (kq == 0) h3[o * 14 + s] = fmaxf(acc + cC_b3[o], 0.0f);
    }
    __syncthreads();

    // P14: final (1,7) conv over this WG's 2 rows.
    if (t < 16) {
        int r = t >> 3, c = t & 7;           // local row, channel
        float p = 0.0f;
#pragma unroll
        for (int w = 0; w < 7; ++w)
            p = fmaf(cC_w4[c * 7 + w], h3[c * 14 + r * 7 + w], p);
#pragma unroll
        for (int off = 1; off < 8; off <<= 1) p += __shfl_xor(p, off);
        if (c == 0) out[wg * 2 + r] = p + cC_b4[0];
    }
}

extern "C" void kernel_launch(void* const* d_in, const int* in_sizes, int n_in,
                              void* d_out, int out_size, void* d_ws, size_t ws_size,
                              hipStream_t stream) {
    (void)in_sizes; (void)n_in; (void)d_ws; (void)ws_size; (void)out_size;
    const float* a[33];
    for (int i = 0; i < 33; ++i) a[i] = (const float*)d_in[i];
    frap_kernel<<<dim3(4), dim3(512), 0, stream>>>(
        a[0], a[1], a[2], a[3], a[4], a[5], a[6],
        a[7], a[8], a[9], a[10], a[11], a[12],
        a[13], a[14], a[15], a[16], a[17], a[18],
        a[19], a[20], a[21], a[22], a[23], a[24],
        a[25], a[26], a[27], a[28], a[29], a[30], a[31], a[32],
        (float*)d_out);
}